// Round 12
// baseline (110.293 us; speedup 1.0000x reference)
//
#include <hip/hip_runtime.h>
#include <stdint.h>

typedef _Float16 half8 __attribute__((ext_vector_type(8)));
typedef _Float16 half2v __attribute__((ext_vector_type(2)));
typedef __attribute__((ext_vector_type(4))) float floatx4;
typedef __attribute__((ext_vector_type(4))) int intx4;

// ---------------------------------------------------------------------------
// Threefry-2x32 (20 rounds), bit-exact vs JAX (verified r2: absmax 0.0).
// ---------------------------------------------------------------------------
__device__ __forceinline__ void threefry2x32(uint32_t k0, uint32_t k1,
                                             uint32_t& x0, uint32_t& x1) {
  const uint32_t ks2 = k0 ^ k1 ^ 0x1BD11BDAu;
  uint32_t ks[3] = {k0, k1, ks2};
  const int rot[8] = {13, 15, 26, 6, 17, 29, 16, 24};
  x0 += ks[0];
  x1 += ks[1];
#pragma unroll
  for (int i = 0; i < 5; ++i) {
#pragma unroll
    for (int j = 0; j < 4; ++j) {
      const int r = rot[(i & 1) * 4 + j];
      x0 += x1;
      x1 = (x1 << r) | (x1 >> (32 - r));
      x1 ^= x0;
    }
    x0 += ks[(i + 1) % 3];
    x1 += ks[(i + 2) % 3] + (uint32_t)(i + 1);
  }
}

__device__ __forceinline__ float dropmask(int core, int e, float v) {
  uint32_t f0 = 0u, f1 = (uint32_t)core;
  threefry2x32(0u, 42u, f0, f1);
  uint32_t a = 0u, b = (uint32_t)e;
  threefry2x32(f0, f1, a, b);
  uint32_t bits = a ^ b;
  float u = __uint_as_float((bits >> 9) | 0x3F800000u) - 1.0f;
  float m = (u < 0.8f) ? 1.0f : 0.0f;
  return v * m / 0.8f;
}

union H2U { _Float16 h; unsigned short s; };
__device__ __forceinline__ unsigned short f2h(float f) {  // RNE fp32->fp16
  H2U u;
  u.h = (_Float16)f;
  return u.s;
}

union FragH { intx4 i; half8 h; half2v h2[4]; };

// ---------------------------------------------------------------------------
// Prep: masked fp16 B matrices in MFMA B-fragment order (r10-verified
// indexing, r11-verified fp16).
//   bsw1: idx=(c<16,lane,j): k = c*32 + q*8 + j, col o = lane&15
//   bsw2: idx=(c<45,lane,j): t = 45q + c, m = t/5, nk = 8*(t%5)+j
//         (zeros for nk>=36 or o>=10). K' = 1440.
// Also zero-inits out (linear_kernel accumulates with atomics).
// ---------------------------------------------------------------------------
__global__ void prep_kernel(const float* __restrict__ eps0,
                            const float* __restrict__ eps1,
                            unsigned short* __restrict__ bsw1,
                            unsigned short* __restrict__ bsw2,
                            float* __restrict__ out) {
  int idx = blockIdx.x * 256 + threadIdx.x;  // grid exactly 31232
  if (idx < 1280) out[idx] = 0.0f;
  if (idx < 8192) {
    int j = idx & 7, L = (idx >> 3) & 63, c = idx >> 9;
    int o = L & 15, q = L >> 4;
    int k = c * 32 + q * 8 + j;
    float v = 0.0f;
    if (o < 6) {
      int e = o * 512 + k;
      v = dropmask(0, e, eps0[e]);
    }
    bsw1[idx] = f2h(v);
  } else {
    int t2 = idx - 8192;  // < 23040 = 45*512
    int j = t2 & 7, L = (t2 >> 3) & 63, c = t2 >> 9;
    int o = L & 15, q = L >> 4;
    int t = 45 * q + c;
    int m = t / 5, nk = 8 * (t % 5) + j;
    float v = 0.0f;
    if (o < 10 && nk < 36) {
      int e = o * 1296 + m * 36 + nk;
      v = dropmask(1, e, eps1[e]);
    }
    bsw2[t2] = f2h(v);
  }
}

// 6-way select, cndmask chain (runtime k, constant element indices)
__device__ __forceinline__ float sel6(const float a[6], int k) {
  float r = a[0];
  r = (k == 1) ? a[1] : r;
  r = (k == 2) ? a[2] : r;
  r = (k == 3) ? a[3] : r;
  r = (k == 4) ? a[4] : r;
  r = (k == 5) ? a[5] : r;
  return r;
}

// ---------------------------------------------------------------------------
// Stage 1: NO LDS. __launch_bounds__(256,4) -> VGPR<=128, 16 waves/CU (50%).
// B1 fully register-resident (16 x intx4 = 64 VGPR, fits the 128 cap).
// K-loop: pure VALU(pk_mul_f16)+MFMA, zero memory ops.
// ---------------------------------------------------------------------------
__global__ __launch_bounds__(256, 4) void stage1_mfma(
    const float* __restrict__ x, const unsigned short* __restrict__ bsw1,
    float* __restrict__ h) {
  const int lane = threadIdx.x & 63;
  const int wave = (blockIdx.x * 256 + threadIdx.x) >> 6;  // 0..5407
  const int col = lane & 15, q = lane >> 4;

  intx4 bfr1[16];
  const intx4* bsrc1 = (const intx4*)bsw1 + lane;
#pragma unroll
  for (int c = 0; c < 16; ++c) bfr1[c] = bsrc1[c * 64];

  const int pid = wave * 16 + col;
  const int b = pid / 676;
  const int rem = pid - b * 676;
  const int ii = rem / 26;
  const int jj = rem - ii * 26;

  const float2* x2 = (const float2*)x;
  float xv[9][2];
#pragma unroll
  for (int di = 0; di < 3; ++di)
#pragma unroll
    for (int dj = 0; dj < 3; ++dj) {
      float2 v = x2[(b * 28 + ii + di) * 28 + (jj + dj)];
      xv[di * 3 + dj][0] = v.x;
      xv[di * 3 + dj][1] = v.y;
    }

  // w3 packed fp16 pairs
  half2v w3p[4];
#pragma unroll
  for (int p2 = 0; p2 < 4; ++p2) {
    const int j0 = 2 * p2, j1 = j0 + 1;
    const float a0 = xv[6][(j0 >> 2) & 1] * xv[7][(j0 >> 1) & 1] * xv[8][j0 & 1];
    const float a1 = xv[6][(j1 >> 2) & 1] * xv[7][(j1 >> 1) & 1] * xv[8][j1 & 1];
    w3p[p2] = half2v{(_Float16)a0, (_Float16)a1};
  }

  const float wq = xv[4][(q >> 1) & 1] * xv[5][q & 1];
  float t01[4], t23[4];
#pragma unroll
  for (int a = 0; a < 2; ++a)
#pragma unroll
    for (int d = 0; d < 2; ++d) {
      t01[a * 2 + d] = xv[0][a] * xv[1][d];
      t23[a * 2 + d] = xv[2][a] * xv[3][d] * wq;
    }

  floatx4 acc0 = {0.f, 0.f, 0.f, 0.f};
  floatx4 acc1 = {0.f, 0.f, 0.f, 0.f};
#pragma unroll
  for (int c = 0; c < 16; ++c) {
    FragH bf;
    bf.i = bfr1[c];
    const _Float16 wh = (_Float16)(t01[c >> 2] * t23[c & 3]);
    const half2v w2 = {wh, wh};
    FragH af;
    af.h2[0] = w2 * w3p[0];
    af.h2[1] = w2 * w3p[1];
    af.h2[2] = w2 * w3p[2];
    af.h2[3] = w2 * w3p[3];
    if (c & 1)
      acc1 = __builtin_amdgcn_mfma_f32_16x16x32_f16(af.h, bf.h, acc1, 0, 0, 0);
    else
      acc0 = __builtin_amdgcn_mfma_f32_16x16x32_f16(af.h, bf.h, acc0, 0, 0, 0);
  }
  const floatx4 acc = acc0 + acc1;
  if (col < 6) {
#pragma unroll
    for (int r = 0; r < 4; ++r) h[(wave * 16 + q * 4 + r) * 6 + col] = acc[r];
  }
}

// ---------------------------------------------------------------------------
// Stage 2: NO LDS. __launch_bounds__(256,4) -> VGPR<=128, 16 waves/CU.
// B2 streamed from global through an 8-deep register ring (32 VGPR,
// compile-time indices via full unroll) -> 8 loads in flight covers L2
// latency. A-octet: 1 cvt + 4 v_pk_mul_f16 from per-tile packed P23 pairs.
// ---------------------------------------------------------------------------
__global__ __launch_bounds__(256, 4) void stage2_mfma(
    const float* __restrict__ h, const unsigned short* __restrict__ bsw2,
    float* __restrict__ flat) {
  const int lane = threadIdx.x & 63;
  const int wave = (blockIdx.x * 256 + threadIdx.x) >> 6;  // 0..4999
  const int col = lane & 15, q = lane >> 4;
  const int pid = wave * 16 + col;
  const int b = pid / 625;
  const int rem = pid - b * 625;
  const int ii = rem / 25;
  const int jj = rem - ii * 25;

  // prime the ring early (8 loads in flight while we do tile setup)
  const intx4* bsrc = (const intx4*)bsw2 + lane;
  intx4 ring[8];
#pragma unroll
  for (int c = 0; c < 8; ++c) ring[c] = bsrc[c * 64];

  const float* hp = h + ((b * 26 + ii) * 26 + jj) * 6;
  float h00[6], h01[6], h10[6], h11[6];
  const float2* hp2a = (const float2*)(hp);
  const float2* hp2b = (const float2*)(hp + 156);
#pragma unroll
  for (int t = 0; t < 3; ++t) {
    float2 v0 = hp2a[t], v1 = hp2a[t + 3], v2 = hp2b[t], v3 = hp2b[t + 3];
    h00[2 * t] = v0.x; h00[2 * t + 1] = v0.y;
    h01[2 * t] = v1.x; h01[2 * t + 1] = v1.y;
    h10[2 * t] = v2.x; h10[2 * t + 1] = v2.y;
    h11[2 * t] = v3.x; h11[2 * t + 1] = v3.y;
  }

  // P23[40] as 20 packed fp16 pairs (last 2 pairs are the n-pad zeros)
  half2v p23p[20];
#pragma unroll
  for (int t = 0; t < 18; ++t) {
    const int n0 = 2 * t, n1 = 2 * t + 1;
    const float f0 = h10[n0 / 6] * h11[n0 % 6];
    const float f1 = h10[n1 / 6] * h11[n1 % 6];
    p23p[t] = half2v{(_Float16)f0, (_Float16)f1};
  }
  p23p[18] = half2v{(_Float16)0.f, (_Float16)0.f};
  p23p[19] = half2v{(_Float16)0.f, (_Float16)0.f};

  // P01 subset for this lane: m = 9q + d
  float P01s[9];
#pragma unroll
  for (int d = 0; d < 9; ++d) {
    const int m = 9 * q + d;
    const int ia = (m * 43) >> 8;  // m/6 exact for m < 54
    const int ic = m - ia * 6;
    P01s[d] = sel6(h00, ia) * sel6(h01, ic);
  }

  floatx4 acc0 = {0.f, 0.f, 0.f, 0.f};
  floatx4 acc1 = {0.f, 0.f, 0.f, 0.f};
#pragma unroll
  for (int c = 0; c < 45; ++c) {  // chunk c: m = 9q + c/5, n0 = 8*(c%5)
    FragH bf;
    bf.i = ring[c & 7];
    if (c + 8 < 45) ring[c & 7] = bsrc[(c + 8) * 64];  // refill ring slot
    const _Float16 ph = (_Float16)P01s[c / 5];
    const half2v p2 = {ph, ph};
    const int pb = 4 * (c % 5);
    FragH af;
    af.h2[0] = p2 * p23p[pb + 0];
    af.h2[1] = p2 * p23p[pb + 1];
    af.h2[2] = p2 * p23p[pb + 2];
    af.h2[3] = p2 * p23p[pb + 3];
    if (c & 1)
      acc1 = __builtin_amdgcn_mfma_f32_16x16x32_f16(af.h, bf.h, acc1, 0, 0, 0);
    else
      acc0 = __builtin_amdgcn_mfma_f32_16x16x32_f16(af.h, bf.h, acc0, 0, 0, 0);
  }
  const floatx4 acc = acc0 + acc1;
  if (col < 10) {
#pragma unroll
    for (int r = 0; r < 4; ++r)
      flat[(wave * 16 + q * 4 + r) * 10 + col] = acc[r];
  }
}

// ---------------------------------------------------------------------------
// Linear, split over f: grid (128, 5). Block-reduce + one atomicAdd per o.
// out zero-initialized by prep_kernel.
// ---------------------------------------------------------------------------
__global__ __launch_bounds__(256) void linear_kernel(
    const float* __restrict__ flat, const float* __restrict__ W,
    const float* __restrict__ bias, float* __restrict__ out) {
  const int b = blockIdx.x;
  const int c = blockIdx.y;  // 0..4
  const float* fb = flat + b * 6250 + c * 1250;
  const float* Wc = W + c * 1250;
  float acc[10];
#pragma unroll
  for (int o = 0; o < 10; ++o) acc[o] = 0.0f;
  for (int f = threadIdx.x; f < 1250; f += 256) {
    const float v = fb[f];
#pragma unroll
    for (int o = 0; o < 10; ++o) acc[o] += v * Wc[o * 6250 + f];
  }
#pragma unroll
  for (int o = 0; o < 10; ++o) {
#pragma unroll
    for (int s = 32; s > 0; s >>= 1) acc[o] += __shfl_xor(acc[o], s, 64);
  }
  __shared__ float red[4][10];
  const int lane = threadIdx.x & 63, wv = threadIdx.x >> 6;
  if (lane == 0) {
#pragma unroll
    for (int o = 0; o < 10; ++o) red[wv][o] = acc[o];
  }
  __syncthreads();
  if (threadIdx.x < 10) {
    const int o = threadIdx.x;
    float r = red[0][o] + red[1][o] + red[2][o] + red[3][o];
    if (c == 0) r += bias[o];
    atomicAdd(&out[b * 10 + o], r);
  }
}

// ---------------------------------------------------------------------------
extern "C" void kernel_launch(void* const* d_in, const int* in_sizes, int n_in,
                              void* d_out, int out_size, void* d_ws,
                              size_t ws_size, hipStream_t stream) {
  const float* x = (const float*)d_in[0];     // (128,28,28,2)
  const float* eps0 = (const float*)d_in[1];  // (6,512)
  const float* eps1 = (const float*)d_in[2];  // (10,1296)
  const float* W = (const float*)d_in[3];     // (10,6250)
  const float* bias = (const float*)d_in[4];  // (10,)
  float* out = (float*)d_out;                 // (128,10)

  char* wsb = (char*)d_ws;
  unsigned short* bsw1 = (unsigned short*)wsb;            // 16384 B
  unsigned short* bsw2 = (unsigned short*)(wsb + 16384);  // 46080 B
  float* h = (float*)(wsb + 65536);               // 519168 floats
  float* flat = (float*)(wsb + 65536 + 2076672);  // 800000 floats

  hipLaunchKernelGGL(prep_kernel, dim3(122), dim3(256), 0, stream, eps0, eps1,
                     bsw1, bsw2, out);
  hipLaunchKernelGGL(stage1_mfma, dim3(1352), dim3(256), 0, stream, x, bsw1,
                     h);
  hipLaunchKernelGGL(stage2_mfma, dim3(1250), dim3(256), 0, stream, h, bsw2,
                     flat);
  hipLaunchKernelGGL(linear_kernel, dim3(128, 5), dim3(256), 0, stream, flat,
                     W, bias, out);
}